// Round 11
// baseline (106.111 us; speedup 1.0000x reference)
//
#include <hip/hip_runtime.h>
#include <stdint.h>

#define VOCAB 32000
#define KDIM  2048   // 2*HIDDEN
#define NDIM  1024   // HIDDEN
#define MTOK  16384  // 4*4096

typedef __bf16 bf16x8 __attribute__((ext_vector_type(8)));
typedef float  f32x4  __attribute__((ext_vector_type(4)));

__device__ __forceinline__ uint32_t pkbf(float a, float b) {
    union { __bf16 h[2]; uint32_t u; } r;
    r.h[0] = (__bf16)a; r.h[1] = (__bf16)b;
    return r.u;
}

__device__ __forceinline__ unsigned short f2bf(float f) {  // fallback path only
    union { float f; uint32_t u; } v; v.f = f;
    uint32_t u = v.u;
    return (unsigned short)((u + 0x7FFFu + ((u >> 16) & 1u)) >> 16);
}

// width-16 global->LDS DMA: per-lane global src, wave-uniform LDS base.
__device__ __forceinline__ void gload_lds16(const void* g, void* l) {
    __builtin_amdgcn_global_load_lds(
        (const __attribute__((address_space(1))) uint32_t*)g,
        (__attribute__((address_space(3))) uint32_t*)l,
        16, 0, 0);
}

// ---------------------------------------------------------------------------
// One-time transpose+convert: W1 [K][N] f32 -> W1T [N][K] bf16
// ---------------------------------------------------------------------------
__global__ void w1_transpose_kernel(const float* __restrict__ W1,
                                    unsigned short* __restrict__ W1T) {
    __shared__ unsigned short tile[32][33];
    const int k0 = blockIdx.x * 32;
    const int n0 = blockIdx.y * 32;
    const int tx = threadIdx.x;
    const int ty = threadIdx.y;
#pragma unroll
    for (int i = 0; i < 4; ++i) {
        int kl = ty + i * 8;
        tile[kl][tx] = __builtin_bit_cast(unsigned short,
                            (__bf16)W1[(size_t)(k0 + kl) * NDIM + n0 + tx]);
    }
    __syncthreads();
#pragma unroll
    for (int i = 0; i < 4; ++i) {
        int nl = ty + i * 8;
        W1T[(size_t)(n0 + nl) * KDIM + k0 + tx] = tile[tx][nl];
    }
}

// ---------------------------------------------------------------------------
// 128x128 fused gather-GEMM, 2 BLOCKS/CU for LDS<->MFMA overlap via block
// independence (R7's 1-block/CU lockstep left the pipes alternating).
// BK=64, 256 thr = 4 waves (2M x 2N), wave tile 64x64 (4x4 frags of
// 16x16x32), acc = 64 AGPR. LDS = A+B dbuf = 64 KB -> 2 blocks/CU,
// 8 waves/CU, VGPR budget 256/wave -> room for full frag read-ahead:
// ks1 frags are read BEFORE the ks0 MFMA cluster (service hides under it).
// A: gathered W0 rows, fp32->bf16 in regs, ds_write (half-gathers, T14).
// B: global_load_lds w16 from W1T, pre-swizzled source (rule 21).
// XOR swizzle byte^=(r&7)<<4 on both tiles (2-way alias = free).
// One __syncthreads per K-tile; all staging targets buf[nxt].
// ---------------------------------------------------------------------------
__global__ __launch_bounds__(256, 2)
void emb_gemm_ws(const int* __restrict__ idx,
                 const float* __restrict__ W0,
                 const unsigned short* __restrict__ W1T,
                 float* __restrict__ out) {
    __shared__ __align__(16) char Abuf[2][128 * 128];  // 128 rows x 64 bf16
    __shared__ __align__(16) char Bbuf[2][128 * 128];

    const int tid  = threadIdx.x;   // 0..255
    const int lane = tid & 63;
    const int wav  = tid >> 6;      // 0..3
    const int wm   = wav >> 1;      // 0..1
    const int wn   = wav & 1;       // 0..1
    const int m0   = blockIdx.x * 128;
    const int n0   = blockIdx.y * 128;

    const int rl = lane & 15;
    const int kg = (lane >> 4) * 16;  // 16B k-subchunk within 64B half

    // ---- A gather: 8 chunks/thread (16B fp32 -> 8B bf16), rows 0..127 ----
    const int ac = tid & 15;
    uint32_t aoff[8];
    int abyte[8];
#pragma unroll
    for (int it = 0; it < 8; ++it) {
        const int r = (tid >> 4) + it * 16;          // 0..127
        aoff[it]  = ((uint32_t)idx[m0 + r] * KDIM + ac * 4) * 4u;
        abyte[it] = (r * 128 + ac * 8) ^ ((r & 7) << 4);
    }

    // ---- B staging: 4 gload_lds/wave (8 rows each), pre-swizzled source ----
    const int brin = lane >> 3;
    const int bch  = (lane & 7) ^ brin;
    uint32_t boff[4];
    int bbase[4];
#pragma unroll
    for (int i = 0; i < 4; ++i) {
        const int rg = wav * 32 + i * 8;  // 4 waves x 32 rows = 128
        boff[i]  = ((uint32_t)(n0 + rg + brin) * KDIM + bch * 8) * 2u;
        bbase[i] = rg * 128;
    }

    f32x4 apre[4];           // one half-gather live at a time
    f32x4 acc[4][4] = {};    // 64 AGPR
    bf16x8 afX[4], afY[4], bfX[4], bfY[4];

#define ISSUE_A_H(t, h)                                              \
    _Pragma("unroll")                                                \
    for (int j = 0; j < 4; ++j)                                      \
        apre[j] = *(const f32x4*)((const char*)W0 + aoff[(h) * 4 + j] + (t) * 256);

#define WRITE_A_H(buf, h)                                            \
    _Pragma("unroll")                                                \
    for (int j = 0; j < 4; ++j) {                                    \
        uint2 pk_;                                                   \
        pk_.x = pkbf(apre[j][0], apre[j][1]);                        \
        pk_.y = pkbf(apre[j][2], apre[j][3]);                        \
        *(uint2*)(Abuf[buf] + abyte[(h) * 4 + j]) = pk_;             \
    }

#define DMA_B(buf, t)                                                \
    _Pragma("unroll")                                                \
    for (int i = 0; i < 4; ++i)                                      \
        gload_lds16((const char*)W1T + boff[i] + (t) * 128,          \
                    Bbuf[buf] + bbase[i]);

#define READ_A(buf, ks, dst)                                         \
    _Pragma("unroll")                                                \
    for (int mi = 0; mi < 4; ++mi) {                                 \
        const int r = wm * 64 + mi * 16 + rl;                        \
        dst[mi] = *(const bf16x8*)(Abuf[buf] +                       \
            ((r * 128 + (ks) * 64 + kg) ^ ((r & 7) << 4)));          \
    }

#define READ_B(buf, ks, dst)                                         \
    _Pragma("unroll")                                                \
    for (int ni = 0; ni < 4; ++ni) {                                 \
        const int n = wn * 64 + ni * 16 + rl;                        \
        dst[ni] = *(const bf16x8*)(Bbuf[buf] +                       \
            ((n * 128 + (ks) * 64 + kg) ^ ((n & 7) << 4)));          \
    }

#define MFMA16(a_, b_)                                               \
    __builtin_amdgcn_s_setprio(1);                                   \
    _Pragma("unroll")                                                \
    for (int mi = 0; mi < 4; ++mi)                                   \
        _Pragma("unroll")                                            \
        for (int ni = 0; ni < 4; ++ni)                               \
            acc[mi][ni] = __builtin_amdgcn_mfma_f32_16x16x32_bf16(   \
                a_[mi], b_[ni], acc[mi][ni], 0, 0, 0);               \
    __builtin_amdgcn_s_setprio(0);

    // ---- prologue: stage K-tile 0 into buf0 ----
    DMA_B(0, 0);
    ISSUE_A_H(0, 0); WRITE_A_H(0, 0);
    ISSUE_A_H(0, 1); WRITE_A_H(0, 1);   // vmcnt wait also retires B DMA
    __syncthreads();

    // ---- main loop: 32 K-tiles ----
    for (int t = 0; t < 32; ++t) {
        const int cur = t & 1, nxt = cur ^ 1;
        const bool pf = (t < 31);

        if (pf) { DMA_B(nxt, t + 1); ISSUE_A_H(t + 1, 0); }

        // read BOTH k-halves up front: ks1 services under the ks0 MFMAs
        READ_A(cur, 0, afX); READ_B(cur, 0, bfX);
        READ_A(cur, 1, afY); READ_B(cur, 1, bfY);

        MFMA16(afX, bfX);

        if (pf) { WRITE_A_H(nxt, 0); ISSUE_A_H(t + 1, 1); }

        MFMA16(afY, bfY);

        if (pf) { WRITE_A_H(nxt, 1); }
        __syncthreads();
    }

    // ---- epilogue: mask (token==0) and scale by 32 = sqrt(1024) ----
    const int rowq = (lane >> 4) * 4;
#pragma unroll
    for (int mi = 0; mi < 4; ++mi) {
#pragma unroll
        for (int r = 0; r < 4; ++r) {
            const int m = m0 + wm * 64 + mi * 16 + rowq + r;
            const float msk = (idx[m] != 0) ? 32.0f : 0.0f;
#pragma unroll
            for (int ni = 0; ni < 4; ++ni) {
                const int n = n0 + wn * 64 + ni * 16 + rl;
                out[(size_t)m * NDIM + n] = acc[mi][ni][r] * msk;
            }
        }
    }
#undef ISSUE_A_H
#undef WRITE_A_H
#undef DMA_B
#undef READ_A
#undef READ_B
#undef MFMA16
}

// ---------------------------------------------------------------------------
// Fallback (ws too small): single-buffer, transpose-on-stage from W1 fp32.
// ---------------------------------------------------------------------------
__global__ __launch_bounds__(256)
void emb_gemm_nows(const int* __restrict__ idx,
                   const float* __restrict__ W0,
                   const float* __restrict__ W1,
                   float* __restrict__ out) {
    __shared__ __align__(16) char A_lds[128 * 128];
    __shared__ __align__(16) char B_lds[128 * 128];

    const int tid  = threadIdx.x;
    const int lane = tid & 63;
    const int wav  = tid >> 6;
    const int wm = wav >> 1;
    const int wn = wav & 1;
    const int m0 = blockIdx.x * 128;
    const int n0 = blockIdx.y * 128;

    const float* aSrc[8];
    int arow[8];
#pragma unroll
    for (int it = 0; it < 8; ++it) {
        int r = it * 16 + (tid >> 4);
        arow[it] = r;
        aSrc[it] = W0 + (size_t)idx[m0 + r] * KDIM;
    }
    const int acol4 = tid & 15;

    f32x4 acc[4][4] = {};

    for (int k0 = 0; k0 < KDIM; k0 += 64) {
#pragma unroll
        for (int it = 0; it < 8; ++it) {
            const int r = arow[it];
            const float4 v = *(const float4*)(aSrc[it] + k0 + acol4 * 4);
            uint2 pk;
            pk.x = pkbf(v.x, v.y);
            pk.y = pkbf(v.z, v.w);
            *(uint2*)(A_lds + ((r * 128 + acol4 * 8) ^ ((r & 7) << 4))) = pk;
        }
#pragma unroll
        for (int it = 0; it < 8; ++it) {
            const int k  = it * 8 + (tid >> 5);
            const int n4 = (tid & 31) * 4;
            const float4 v = *(const float4*)(W1 + (size_t)(k0 + k) * NDIM + n0 + n4);
            unsigned short h[4] = { f2bf(v.x), f2bf(v.y), f2bf(v.z), f2bf(v.w) };
#pragma unroll
            for (int i = 0; i < 4; ++i) {
                const int n = n4 + i;
                *(unsigned short*)(B_lds + ((n * 128 + k * 2) ^ ((n & 7) << 4))) = h[i];
            }
        }
        __syncthreads();

#pragma unroll
        for (int ks = 0; ks < 2; ++ks) {
            const int kb = ks * 64 + (lane >> 4) * 16;
            bf16x8 af[4], bfv[4];
#pragma unroll
            for (int mi = 0; mi < 4; ++mi) {
                const int r = wm * 64 + mi * 16 + (lane & 15);
                af[mi] = *(const bf16x8*)(A_lds + ((r * 128 + kb) ^ ((r & 7) << 4)));
            }
#pragma unroll
            for (int ni = 0; ni < 4; ++ni) {
                const int n = wn * 64 + ni * 16 + (lane & 15);
                bfv[ni] = *(const bf16x8*)(B_lds + ((n * 128 + kb) ^ ((n & 7) << 4)));
            }
#pragma unroll
            for (int mi = 0; mi < 4; ++mi)
#pragma unroll
                for (int ni = 0; ni < 4; ++ni)
                    acc[mi][ni] = __builtin_amdgcn_mfma_f32_16x16x32_bf16(
                        af[mi], bfv[ni], acc[mi][ni], 0, 0, 0);
        }
        __syncthreads();
    }

    const int col  = lane & 15;
    const int rowq = (lane >> 4) * 4;
#pragma unroll
    for (int mi = 0; mi < 4; ++mi) {
#pragma unroll
        for (int r = 0; r < 4; ++r) {
            const int m = m0 + wm * 64 + mi * 16 + rowq + r;
            const float msk = (idx[m] != 0) ? 32.0f : 0.0f;
#pragma unroll
            for (int ni = 0; ni < 4; ++ni) {
                const int n = n0 + wn * 64 + ni * 16 + col;
                out[(size_t)m * NDIM + n] = acc[mi][ni][r] * msk;
            }
        }
    }
}

extern "C" void kernel_launch(void* const* d_in, const int* in_sizes, int n_in,
                              void* d_out, int out_size, void* d_ws, size_t ws_size,
                              hipStream_t stream) {
    const int*   idx = (const int*)d_in[0];
    const float* W0  = (const float*)d_in[1];
    const float* W1  = (const float*)d_in[2];
    float*       out = (float*)d_out;

    const size_t w1t_bytes = (size_t)KDIM * NDIM * 2;

    if (ws_size >= w1t_bytes) {
        unsigned short* W1T = (unsigned short*)d_ws;
        dim3 tgrid(KDIM / 32, NDIM / 32);
        w1_transpose_kernel<<<tgrid, dim3(32, 8), 0, stream>>>(W1, W1T);
        dim3 grid(MTOK / 128, NDIM / 128);  // (128, 8) = 1024 blocks
        emb_gemm_ws<<<grid, 256, 0, stream>>>(idx, W0, W1T, out);
    } else {
        dim3 grid(MTOK / 128, NDIM / 128);
        emb_gemm_nows<<<grid, 256, 0, stream>>>(idx, W0, W1, out);
    }
}

// Round 12
// 88.846 us; speedup vs baseline: 1.1943x; 1.1943x over previous
//
#include <hip/hip_runtime.h>
#include <stdint.h>

#define VOCAB 32000
#define KDIM  2048   // 2*HIDDEN
#define NDIM  1024   // HIDDEN
#define MTOK  16384  // 4*4096

typedef __bf16 bf16x8 __attribute__((ext_vector_type(8)));
typedef float  f32x4  __attribute__((ext_vector_type(4)));

__device__ __forceinline__ uint32_t pkbf(float a, float b) {
    union { __bf16 h[2]; uint32_t u; } r;
    r.h[0] = (__bf16)a; r.h[1] = (__bf16)b;
    return r.u;
}

__device__ __forceinline__ unsigned short f2bf(float f) {  // fallback path only
    union { float f; uint32_t u; } v; v.f = f;
    uint32_t u = v.u;
    return (unsigned short)((u + 0x7FFFu + ((u >> 16) & 1u)) >> 16);
}

// width-16 global->LDS DMA: per-lane global src, wave-uniform LDS base.
__device__ __forceinline__ void gload_lds16(const void* g, void* l) {
    __builtin_amdgcn_global_load_lds(
        (const __attribute__((address_space(1))) uint32_t*)g,
        (__attribute__((address_space(3))) uint32_t*)l,
        16, 0, 0);
}

// ---------------------------------------------------------------------------
// One-time transpose+convert: W1 [K][N] f32 -> W1T [N][K] bf16
// ---------------------------------------------------------------------------
__global__ void w1_transpose_kernel(const float* __restrict__ W1,
                                    unsigned short* __restrict__ W1T) {
    __shared__ unsigned short tile[32][33];
    const int k0 = blockIdx.x * 32;
    const int n0 = blockIdx.y * 32;
    const int tx = threadIdx.x;
    const int ty = threadIdx.y;
#pragma unroll
    for (int i = 0; i < 4; ++i) {
        int kl = ty + i * 8;
        tile[kl][tx] = __builtin_bit_cast(unsigned short,
                            (__bf16)W1[(size_t)(k0 + kl) * NDIM + n0 + tx]);
    }
    __syncthreads();
#pragma unroll
    for (int i = 0; i < 4; ++i) {
        int nl = ty + i * 8;
        W1T[(size_t)(n0 + nl) * KDIM + k0 + tx] = tile[tx][nl];
    }
}

// ---------------------------------------------------------------------------
// 256x256 fused gather-GEMM — R7 structure (best: 89.3us) + WAVE-PARITY
// K-HALF SKEW: odd waves consume ks order (1,0), even waves (0,1). All of
// buf[cur] is resident post-barrier, so this is legal; per-thread fp32
// accumulation order is fixed -> deterministic. Effect: post-barrier the two
// wave groups read DISJOINT LDS regions and their MFMA clusters anti-phase,
// so one group's MFMA covers the other's ds_read burst (breaks the
// read-burst/MFMA lockstep that made LDS and MFMA pipes serialize).
// Everything else identical to R7: BK=64, 512 thr = 8 waves (2M x 4N),
// wave tile 128x64, acc 128 AGPR, dbuf LDS 128 KB, one __syncthreads per
// tile, A half-gathers (fp32->bf16 in regs, T14), B via global_load_lds
// with pre-swizzled source (rule 21), XOR swizzle byte^=(r&7)<<4.
// ---------------------------------------------------------------------------
__global__ __launch_bounds__(512, 2)
void emb_gemm_ws(const int* __restrict__ idx,
                 const float* __restrict__ W0,
                 const unsigned short* __restrict__ W1T,
                 float* __restrict__ out) {
    __shared__ __align__(16) char Abuf[2][256 * 128];  // 256 rows x 64 bf16
    __shared__ __align__(16) char Bbuf[2][256 * 128];

    const int tid  = threadIdx.x;   // 0..511
    const int lane = tid & 63;
    const int wav  = tid >> 6;      // 0..7
    const int wm   = wav >> 2;      // 0..1  (M half: 128 rows)
    const int wn   = wav & 3;       // 0..3  (N quarter: 64 cols)
    const int m0   = blockIdx.x * 256;
    const int n0   = blockIdx.y * 256;

    const int rl = lane & 15;
    const int kg = (lane >> 4) * 16;  // 16B k-subchunk within 64B half

    // wave-parity K-half skew
    const int ka = wav & 1;
    const int kb = ka ^ 1;

    // ---- A gather setup: 8 chunks/thread (16B fp32 -> 8B bf16) ----
    const int ac = tid & 15;
    uint32_t aoff[8];
    int abyte[8];
#pragma unroll
    for (int it = 0; it < 8; ++it) {
        const int r = (tid >> 4) + it * 32;          // 0..255
        aoff[it]  = ((uint32_t)idx[m0 + r] * KDIM + ac * 4) * 4u;
        abyte[it] = (r * 128 + ac * 8) ^ ((r & 7) << 4);
    }

    // ---- B staging: 4 gload_lds/wave (8 rows each), pre-swizzled source ----
    const int brin = lane >> 3;
    const int bch  = (lane & 7) ^ brin;
    uint32_t boff[4];
    int bbase[4];
#pragma unroll
    for (int i = 0; i < 4; ++i) {
        const int rg = wav * 32 + i * 8;  // wave-uniform 8-row group base
        boff[i]  = ((uint32_t)(n0 + rg + brin) * KDIM + bch * 8) * 2u;
        bbase[i] = rg * 128;
    }

    f32x4 apre[4];        // one half-gather live at a time (16 VGPR)
    f32x4 acc[8][4] = {};
    bf16x8 af[4], bf2[4], bfv[4];

#define ISSUE_A_H(t, h)                                              \
    _Pragma("unroll")                                                \
    for (int j = 0; j < 4; ++j)                                      \
        apre[j] = *(const f32x4*)((const char*)W0 + aoff[(h) * 4 + j] + (t) * 256);

#define WRITE_A_H(buf, h)                                            \
    _Pragma("unroll")                                                \
    for (int j = 0; j < 4; ++j) {                                    \
        uint2 pk_;                                                   \
        pk_.x = pkbf(apre[j][0], apre[j][1]);                        \
        pk_.y = pkbf(apre[j][2], apre[j][3]);                        \
        *(uint2*)(Abuf[buf] + abyte[(h) * 4 + j]) = pk_;             \
    }

#define DMA_B(buf, t)                                                \
    _Pragma("unroll")                                                \
    for (int i = 0; i < 4; ++i)                                      \
        gload_lds16((const char*)W1T + boff[i] + (t) * 128,          \
                    Bbuf[buf] + bbase[i]);

#define READ_A(buf, ks, mh, dst)                                     \
    _Pragma("unroll")                                                \
    for (int mi = 0; mi < 4; ++mi) {                                 \
        const int r = wm * 128 + (mh) * 64 + mi * 16 + rl;           \
        dst[mi] = *(const bf16x8*)(Abuf[buf] +                       \
            ((r * 128 + (ks) * 64 + kg) ^ ((r & 7) << 4)));          \
    }

#define READ_B(buf, ks, dst)                                         \
    _Pragma("unroll")                                                \
    for (int ni = 0; ni < 4; ++ni) {                                 \
        const int n = wn * 64 + ni * 16 + rl;                        \
        dst[ni] = *(const bf16x8*)(Bbuf[buf] +                       \
            ((n * 128 + (ks) * 64 + kg) ^ ((n & 7) << 4)));          \
    }

#define MFMA16(a_, b_, mh)                                           \
    __builtin_amdgcn_s_setprio(1);                                   \
    _Pragma("unroll")                                                \
    for (int mi = 0; mi < 4; ++mi)                                   \
        _Pragma("unroll")                                            \
        for (int ni = 0; ni < 4; ++ni)                               \
            acc[(mh) * 4 + mi][ni] =                                 \
                __builtin_amdgcn_mfma_f32_16x16x32_bf16(             \
                    a_[mi], b_[ni], acc[(mh) * 4 + mi][ni], 0, 0, 0);\
    __builtin_amdgcn_s_setprio(0);

    // ---- prologue: stage K-tile 0 into buf0 ----
    DMA_B(0, 0);
    ISSUE_A_H(0, 0); WRITE_A_H(0, 0);
    ISSUE_A_H(0, 1); WRITE_A_H(0, 1);   // vmcnt wait also retires B DMA
    __syncthreads();

    // ---- main loop: 32 K-tiles, one barrier per tile, skewed ks order ----
    for (int t = 0; t < 32; ++t) {
        const int cur = t & 1, nxt = cur ^ 1;
        const bool pf = (t < 31);

        // issue next tile's B DMA + first A half-gather up front
        if (pf) { DMA_B(nxt, t + 1); ISSUE_A_H(t + 1, 0); }

        // first K-half (ka: 0 for even waves, 1 for odd)
        READ_B(cur, ka, bfv);
        READ_A(cur, ka, 0, af);
        MFMA16(af, bfv, 0);
        READ_A(cur, ka, 1, af);
        MFMA16(af, bfv, 1);

        // mid-tile staging: write A(t+1) half 0 (loads ~2 clusters old)
        if (pf) { WRITE_A_H(nxt, 0); ISSUE_A_H(t + 1, 1); }

        // second K-half (kb)
        READ_B(cur, kb, bf2);
        READ_A(cur, kb, 0, af);
        MFMA16(af, bf2, 0);
        READ_A(cur, kb, 1, af);
        MFMA16(af, bf2, 1);

        if (pf) { WRITE_A_H(nxt, 1); }
        __syncthreads();   // drains A ds_writes + B DMA; buffer flip
    }

    // ---- epilogue: mask (token==0) and scale by 32 = sqrt(1024) ----
    const int rowq = (lane >> 4) * 4;
#pragma unroll
    for (int mi = 0; mi < 8; ++mi) {
#pragma unroll
        for (int r = 0; r < 4; ++r) {
            const int m = m0 + wm * 128 + mi * 16 + rowq + r;
            const float msk = (idx[m] != 0) ? 32.0f : 0.0f;
#pragma unroll
            for (int ni = 0; ni < 4; ++ni) {
                const int n = n0 + wn * 64 + ni * 16 + rl;
                out[(size_t)m * NDIM + n] = acc[mi][ni][r] * msk;
            }
        }
    }
#undef ISSUE_A_H
#undef WRITE_A_H
#undef DMA_B
#undef READ_A
#undef READ_B
#undef MFMA16
}

// ---------------------------------------------------------------------------
// Fallback (ws too small): single-buffer, transpose-on-stage from W1 fp32.
// ---------------------------------------------------------------------------
__global__ __launch_bounds__(256)
void emb_gemm_nows(const int* __restrict__ idx,
                   const float* __restrict__ W0,
                   const float* __restrict__ W1,
                   float* __restrict__ out) {
    __shared__ __align__(16) char A_lds[128 * 128];
    __shared__ __align__(16) char B_lds[128 * 128];

    const int tid  = threadIdx.x;
    const int lane = tid & 63;
    const int wav  = tid >> 6;
    const int wm = wav >> 1;
    const int wn = wav & 1;
    const int m0 = blockIdx.x * 128;
    const int n0 = blockIdx.y * 128;

    const float* aSrc[8];
    int arow[8];
#pragma unroll
    for (int it = 0; it < 8; ++it) {
        int r = it * 16 + (tid >> 4);
        arow[it] = r;
        aSrc[it] = W0 + (size_t)idx[m0 + r] * KDIM;
    }
    const int acol4 = tid & 15;

    f32x4 acc[4][4] = {};

    for (int k0 = 0; k0 < KDIM; k0 += 64) {
#pragma unroll
        for (int it = 0; it < 8; ++it) {
            const int r = arow[it];
            const float4 v = *(const float4*)(aSrc[it] + k0 + acol4 * 4);
            uint2 pk;
            pk.x = pkbf(v.x, v.y);
            pk.y = pkbf(v.z, v.w);
            *(uint2*)(A_lds + ((r * 128 + acol4 * 8) ^ ((r & 7) << 4))) = pk;
        }
#pragma unroll
        for (int it = 0; it < 8; ++it) {
            const int k  = it * 8 + (tid >> 5);
            const int n4 = (tid & 31) * 4;
            const float4 v = *(const float4*)(W1 + (size_t)(k0 + k) * NDIM + n0 + n4);
            unsigned short h[4] = { f2bf(v.x), f2bf(v.y), f2bf(v.z), f2bf(v.w) };
#pragma unroll
            for (int i = 0; i < 4; ++i) {
                const int n = n4 + i;
                *(unsigned short*)(B_lds + ((n * 128 + k * 2) ^ ((n & 7) << 4))) = h[i];
            }
        }
        __syncthreads();

#pragma unroll
        for (int ks = 0; ks < 2; ++ks) {
            const int kb = ks * 64 + (lane >> 4) * 16;
            bf16x8 af[4], bfv[4];
#pragma unroll
            for (int mi = 0; mi < 4; ++mi) {
                const int r = wm * 64 + mi * 16 + (lane & 15);
                af[mi] = *(const bf16x8*)(A_lds + ((r * 128 + kb) ^ ((r & 7) << 4)));
            }
#pragma unroll
            for (int ni = 0; ni < 4; ++ni) {
                const int n = wn * 64 + ni * 16 + (lane & 15);
                bfv[ni] = *(const bf16x8*)(B_lds + ((n * 128 + kb) ^ ((n & 7) << 4)));
            }
#pragma unroll
            for (int mi = 0; mi < 4; ++mi)
#pragma unroll
                for (int ni = 0; ni < 4; ++ni)
                    acc[mi][ni] = __builtin_amdgcn_mfma_f32_16x16x32_bf16(
                        af[mi], bfv[ni], acc[mi][ni], 0, 0, 0);
        }
        __syncthreads();
    }

    const int col  = lane & 15;
    const int rowq = (lane >> 4) * 4;
#pragma unroll
    for (int mi = 0; mi < 4; ++mi) {
#pragma unroll
        for (int r = 0; r < 4; ++r) {
            const int m = m0 + wm * 64 + mi * 16 + rowq + r;
            const float msk = (idx[m] != 0) ? 32.0f : 0.0f;
#pragma unroll
            for (int ni = 0; ni < 4; ++ni) {
                const int n = n0 + wn * 64 + ni * 16 + col;
                out[(size_t)m * NDIM + n] = acc[mi][ni][r] * msk;
            }
        }
    }
}

extern "C" void kernel_launch(void* const* d_in, const int* in_sizes, int n_in,
                              void* d_out, int out_size, void* d_ws, size_t ws_size,
                              hipStream_t stream) {
    const int*   idx = (const int*)d_in[0];
    const float* W0  = (const float*)d_in[1];
    const float* W1  = (const float*)d_in[2];
    float*       out = (float*)d_out;

    const size_t w1t_bytes = (size_t)KDIM * NDIM * 2;

    if (ws_size >= w1t_bytes) {
        unsigned short* W1T = (unsigned short*)d_ws;
        dim3 tgrid(KDIM / 32, NDIM / 32);
        w1_transpose_kernel<<<tgrid, dim3(32, 8), 0, stream>>>(W1, W1T);
        dim3 grid(MTOK / 256, NDIM / 256);  // (64, 4) = 256 blocks = 1/CU
        emb_gemm_ws<<<grid, 512, 0, stream>>>(idx, W0, W1T, out);
    } else {
        dim3 grid(MTOK / 128, NDIM / 128);
        emb_gemm_nows<<<grid, 256, 0, stream>>>(idx, W0, W1, out);
    }
}